// Round 11
// baseline (244.166 us; speedup 1.0000x reference)
//
#include <hip/hip_runtime.h>
#include <hip/hip_bf16.h>
#include <cstdint>

// Problem constants
#define CIN   256
#define COUT  256
#define NB    8
#define NT    16
#define NH    28
#define NW    28
#define HP    30
#define WP    30

#define XM_ELEMS   ((size_t)NB * NT * HP * WP * CIN)   // 29,491,200 bf16
#define XM_BYTES   (XM_ELEMS * 2)

typedef __bf16 bf16x8 __attribute__((ext_vector_type(8)));
typedef float  f32x4  __attribute__((ext_vector_type(4)));

#define AS1 __attribute__((address_space(1)))
#define AS3 __attribute__((address_space(3)))

static __device__ __forceinline__ unsigned short f2bf(float f) {
    __hip_bfloat16 h = __float2bfloat16(f);
    return __builtin_bit_cast(unsigned short, h);
}

// ---------------------------------------------------------------------------
// Pass 1: xm[b][t][hp][wp][ci] = bf16(x[b][ci][t][h][w] * alpha[b][ci][t])
// ---------------------------------------------------------------------------
__global__ void modulate_kernel(const float* __restrict__ x,
                                const float* __restrict__ alpha,
                                unsigned short* __restrict__ xm) {
    const int ci = threadIdx.x;
    const int blk = blockIdx.x;
    const int hp = blk % 30;
    const int bt = blk / 30;
    unsigned short* row = xm + (size_t)(bt * 900 + hp * 30) * 256;
    if (hp == 0 || hp == 29) {
        #pragma unroll
        for (int wp = 0; wp < 30; ++wp) row[wp * 256 + ci] = 0;
        return;
    }
    const int t = bt & 15, b = bt >> 4;
    const int h = hp - 1;
    const float a = alpha[(b * CIN + ci) * NT + t];
    const float* xrow = x + ((size_t)((b * CIN + ci) * NT + t) * NH + h) * NW;
    row[ci] = 0;
    row[29 * 256 + ci] = 0;
    const float4* xv = (const float4*)xrow;
    #pragma unroll
    for (int q = 0; q < 7; ++q) {
        float4 v = xv[q];
        row[(q * 4 + 1) * 256 + ci] = f2bf(v.x * a);
        row[(q * 4 + 2) * 256 + ci] = f2bf(v.y * a);
        row[(q * 4 + 3) * 256 + ci] = f2bf(v.z * a);
        row[(q * 4 + 4) * 256 + ci] = f2bf(v.w * a);
    }
}

// ---------------------------------------------------------------------------
// Pass 2: wB[tap][co][ci] = bf16(weight[co][ci][tap])
// ---------------------------------------------------------------------------
__global__ void repack_w_kernel(const float* __restrict__ w,
                                unsigned short* __restrict__ wB) {
    const int ci = threadIdx.x;
    const int tap = blockIdx.x >> 8;
    const int co  = blockIdx.x & 255;
    wB[((tap * 256 + co) * 256) + ci] = f2bf(w[(co * 256 + ci) * 9 + tap]);
}

// ---------------------------------------------------------------------------
// Pass 3: 256(co) x 224(n) implicit GEMM, BK=32, K=2304 = 72 kt, TAP-INNER.
// R11: A (weights) fragments loaded DIRECTLY global(L2)->registers -- the
// fa content is provably identical to the old LDS path (pre-swizzle ^ read-
// swizzle cancel). B through 3-deep LDS (48KB) with counted vmcnt (R10).
// LDS traffic/kt: 88KB reads -> 56KB, 32KB writes -> 16KB => MFMA pipe now
// dominant. Per-wave vmem queue at body-j top: [BS(j+1)x2, A(j)x4,
// BS(j+2)x2]; VMW(6) drains BS(j+1); compiler scoreboard inserts the
// counted wait for fa(j) before the MFMA cluster. grid=448, block=512
// (8 waves 4Mx2N, wave 64co x 112n, acc 4x7 = 112 AGPR).
// ---------------------------------------------------------------------------

#define BAR()    __builtin_amdgcn_s_barrier()
#define LGKM0()  asm volatile("s_waitcnt lgkmcnt(0)" ::: "memory")
#define VMW(N)   asm volatile("s_waitcnt vmcnt(" #N ")" ::: "memory")
#define SCHED0() __builtin_amdgcn_sched_barrier(0)
#define PRIO(x)  __builtin_amdgcn_s_setprio(x)

// stage B-tile (tapS,cicS) into buf P: 256(224+dup) rows x 32 k, 2 loads/wave
#define STAGE_B(P) do {                                                       \
    const int kh2 = (tapS * 11) >> 5;                                         \
    const int kw2 = tapS - 3 * kh2;                                           \
    const int bOff = ((kh2 - 1) * 30 + (kw2 - 1)) * 256 + cicS * 32;          \
    _Pragma("unroll") for (int c_ = 0; c_ < 2; ++c_)                          \
        __builtin_amdgcn_global_load_lds(                                     \
            (const AS1 void*)(bL[c_] + bOff),                                 \
            (AS3 void*)(lds + (P)*16384 + (c_*128 + wave*16)*64 + lane*16),   \
            16, 0, 0);                                                        \
    if (++tapS == 9) { tapS = 0; ++cicS; }                                    \
} while (0)

// load A fragments for next kt (tapA,cicA) straight to registers
#define LOADA(S) do {                                                         \
    const unsigned short* ap_ = aRow + tapA * 65536 + cicA * 32;              \
    _Pragma("unroll") for (int m_ = 0; m_ < 4; ++m_)                          \
        fa##S[m_] = *(const bf16x8*)(ap_ + m_ * 4096);                        \
    if (++tapA == 9) { tapA = 0; ++cicA; }                                    \
} while (0)

#define READF_B(S, P) do {                                                    \
    _Pragma("unroll") for (int f_ = 0; f_ < 7; ++f_)                          \
        fb##S[f_] = *(const bf16x8*)(lds + (P)*16384 +                        \
            (wn*112 + f_*16 + l15)*64 + readSwz);                             \
} while (0)

#define MFMA28(S) do {                                                        \
    _Pragma("unroll") for (int m_ = 0; m_ < 4; ++m_)                          \
    _Pragma("unroll") for (int f_ = 0; f_ < 7; ++f_)                          \
        acc[m_][f_] = __builtin_amdgcn_mfma_f32_16x16x32_bf16(                \
            fb##S[f_], fa##S[m_], acc[m_][f_], 0, 0, 0);                      \
} while (0)

// body j: compute CS=frags(j); read fb(j+1) from NBUF; load fa(j+1) from
// global; stage B S(j+3) -> SBUF. VMW(6) drains BS(j+1).
#define BODY_S(CS, NS, NBUF, SBUF) do {                                       \
    VMW(6);                                                                   \
    SCHED0();                                                                 \
    BAR();                                                                    \
    READF_B(NS, NBUF);                                                        \
    LOADA(NS);                                                                \
    STAGE_B(SBUF);                                                            \
    SCHED0();                                                                 \
    PRIO(1); MFMA28(CS); PRIO(0);                                             \
    LGKM0();                                                                  \
    SCHED0();                                                                 \
} while (0)

// tail body: no stage; VMN = counted vmcnt target
#define BODY_N(CS, NS, NBUF, VMN) do {                                        \
    VMW(VMN);                                                                 \
    SCHED0();                                                                 \
    BAR();                                                                    \
    READF_B(NS, NBUF);                                                        \
    LOADA(NS);                                                                \
    SCHED0();                                                                 \
    PRIO(1); MFMA28(CS); PRIO(0);                                             \
    LGKM0();                                                                  \
    SCHED0();                                                                 \
} while (0)

__global__ __launch_bounds__(512, 2) void conv_gemm_kernel(
    const unsigned short* __restrict__ xm,
    const unsigned short* __restrict__ wB,
    float* __restrict__ out) {
    __shared__ __align__(1024) char lds[49152];   // 3 x B 16KB

    const int tid  = threadIdx.x;
    const int wave = tid >> 6;             // 0..7
    const int lane = tid & 63;
    const int l15  = lane & 15;
    const int n0   = blockIdx.x * 224;
    const int wm   = wave >> 1;            // 0..3 co quarter (64)
    const int wn   = wave & 1;             // 0..1 n half (112)

    // ---- A fragment source (global, L2-resident): row + k-slot per lane ----
    const unsigned short* aRow =
        wB + (wm * 64 + l15) * 256 + (lane >> 4) * 8;

    // ---- B staging sources (pre-swizzled ci slot; inverse of read swizzle) ----
    const int swzE = 8 * ((lane & 3) ^ ((lane >> 3) & 3));
    const unsigned short* bL[2];
    #pragma unroll
    for (int c_ = 0; c_ < 2; ++c_) {
        int nl = c_ * 128 + wave * 16 + (lane >> 2);   // 0..255
        nl = nl > 223 ? 223 : nl;                      // pad rows duplicate
        const int n  = n0 + nl;
        const int w_ = n % 28, h_ = (n / 28) % 28, bt = n / 784;
        bL[c_] = xm + (size_t)((bt * 30 + h_ + 1) * 30 + (w_ + 1)) * 256 + swzE;
    }

    // ---- B fragment read base (slot swizzle (row>>1)&3, verified) ----
    const int readSwz = ((lane >> 4) ^ ((l15 >> 1) & 3)) << 4;

    f32x4 acc[4][7];
    #pragma unroll
    for (int i = 0; i < 4; ++i)
        #pragma unroll
        for (int j = 0; j < 7; ++j) acc[i][j] = f32x4{0.f, 0.f, 0.f, 0.f};

    bf16x8 faA[4], fbA[7], faB[4], fbB[7];

    int tapS = 0, cicS = 0;      // B-stage target (kt j+3)
    int tapA = 0, cicA = 0;      // A-load target (kt j+1)

    // ---- prologue ----
    STAGE_B(0);                  // S(0)
    STAGE_B(1);                  // S(1)
    LOADA(A);                    // fa(0)
    STAGE_B(2);                  // S(2)
    VMW(8);                      // drain S(0) (oldest 2)
    SCHED0();
    BAR();
    READF_B(A, 0);               // fb(0)
    LGKM0();
    SCHED0();

    // main: bodies j=0..65, period 6 (buf%3 x set%2)
    #pragma unroll 1
    for (int it = 0; it < 11; ++it) {
        BODY_S(A, B, 1, 0);      // j=6it+0
        BODY_S(B, A, 2, 1);      // j=6it+1
        BODY_S(A, B, 0, 2);      // j=6it+2
        BODY_S(B, A, 1, 0);      // j=6it+3
        BODY_S(A, B, 2, 1);      // j=6it+4
        BODY_S(B, A, 0, 2);      // j=6it+5
    }
    // tail: j=66..68 stage S(69..71); j=69,70 drain; j=71 peel
    BODY_S(A, B, 1, 0);          // j=66
    BODY_S(B, A, 2, 1);          // j=67
    BODY_S(A, B, 0, 2);          // j=68
    BODY_N(B, A, 1, 6);          // j=69: drains S(70)
    BODY_N(A, B, 2, 4);          // j=70: drains S(71), loads fa/fb(71)
    PRIO(1); MFMA28(B); PRIO(0); // j=71

    // ---- C-write: lane holds 4 consecutive n (rows) at one co (col) ----
    #pragma unroll
    for (int f = 0; f < 7; ++f) {
        const int n  = n0 + wn * 112 + f * 16 + ((lane >> 4) << 2);
        const int bt = n / 784;
        const int hw = n - bt * 784;
        const int b = bt >> 4, t = bt & 15;
        float* obase = out + ((size_t)(b * 256) * 16 + t) * 784 + hw;
        #pragma unroll
        for (int m = 0; m < 4; ++m) {
            const int co = wm * 64 + m * 16 + l15;
            *(f32x4*)(obase + (size_t)co * 12544) = acc[m][f];
        }
    }
}

// ---------------------------------------------------------------------------
extern "C" void kernel_launch(void* const* d_in, const int* in_sizes, int n_in,
                              void* d_out, int out_size, void* d_ws, size_t ws_size,
                              hipStream_t stream) {
    const float* x      = (const float*)d_in[0];
    const float* alpha  = (const float*)d_in[1];
    const float* weight = (const float*)d_in[2];
    float* out = (float*)d_out;

    unsigned short* xm = (unsigned short*)d_ws;
    unsigned short* wB = (unsigned short*)((char*)d_ws + XM_BYTES);

    modulate_kernel<<<dim3(NB * NT * HP), dim3(256), 0, stream>>>(x, alpha, xm);
    repack_w_kernel<<<dim3(9 * 256), dim3(256), 0, stream>>>(weight, wB);
    conv_gemm_kernel<<<dim3(448), dim3(512), 0, stream>>>(xm, wB, out);
}

// Round 12
// 158.548 us; speedup vs baseline: 1.5400x; 1.5400x over previous
//
#include <hip/hip_runtime.h>
#include <hip/hip_bf16.h>
#include <cstdint>

// Problem constants
#define CIN   256
#define COUT  256
#define NB    8
#define NT    16
#define NH    28
#define NW    28
#define HP    30
#define WP    30

#define XM_ELEMS   ((size_t)NB * NT * HP * WP * CIN)   // 29,491,200 bf16
#define XM_BYTES   (XM_ELEMS * 2)

typedef __bf16 bf16x8 __attribute__((ext_vector_type(8)));
typedef float  f32x4  __attribute__((ext_vector_type(4)));

#define AS1 __attribute__((address_space(1)))
#define AS3 __attribute__((address_space(3)))

static __device__ __forceinline__ unsigned short f2bf(float f) {
    __hip_bfloat16 h = __float2bfloat16(f);
    return __builtin_bit_cast(unsigned short, h);
}

// ---------------------------------------------------------------------------
// Pass 1: xm[b][t][hp][wp][ci] = bf16(x[b][ci][t][h][w] * alpha[b][ci][t])
// ---------------------------------------------------------------------------
__global__ void modulate_kernel(const float* __restrict__ x,
                                const float* __restrict__ alpha,
                                unsigned short* __restrict__ xm) {
    const int ci = threadIdx.x;
    const int blk = blockIdx.x;
    const int hp = blk % 30;
    const int bt = blk / 30;
    unsigned short* row = xm + (size_t)(bt * 900 + hp * 30) * 256;
    if (hp == 0 || hp == 29) {
        #pragma unroll
        for (int wp = 0; wp < 30; ++wp) row[wp * 256 + ci] = 0;
        return;
    }
    const int t = bt & 15, b = bt >> 4;
    const int h = hp - 1;
    const float a = alpha[(b * CIN + ci) * NT + t];
    const float* xrow = x + ((size_t)((b * CIN + ci) * NT + t) * NH + h) * NW;
    row[ci] = 0;
    row[29 * 256 + ci] = 0;
    const float4* xv = (const float4*)xrow;
    #pragma unroll
    for (int q = 0; q < 7; ++q) {
        float4 v = xv[q];
        row[(q * 4 + 1) * 256 + ci] = f2bf(v.x * a);
        row[(q * 4 + 2) * 256 + ci] = f2bf(v.y * a);
        row[(q * 4 + 3) * 256 + ci] = f2bf(v.z * a);
        row[(q * 4 + 4) * 256 + ci] = f2bf(v.w * a);
    }
}

// ---------------------------------------------------------------------------
// Pass 2: wB[tap][co][ci] = bf16(weight[co][ci][tap])
// ---------------------------------------------------------------------------
__global__ void repack_w_kernel(const float* __restrict__ w,
                                unsigned short* __restrict__ wB) {
    const int ci = threadIdx.x;
    const int tap = blockIdx.x >> 8;
    const int co  = blockIdx.x & 255;
    wB[((tap * 256 + co) * 256) + ci] = f2bf(w[(co * 256 + ci) * 9 + tap]);
}

// ---------------------------------------------------------------------------
// Pass 3: 256(co) x 224(n) implicit GEMM. BK=64 bodies: 36 bodies =
// 9 taps (outer) x 4 ci-64-chunks (inner) -> per body ONE contiguous 64-k
// slab for A and B, ONE VMW(0)+BAR, two 28-MFMA clusters (klo/khi) with
// khi ds_reads issued under the klo MFMA shadow. 2-deep LDS (128KB):
// body j drains S(j) (issued a full body ~4000cy earlier), stages
// S(j+1) into the buffer body j-1 finished reading. Staging/read/swizzle
// formulas verbatim from R3 (128B rows, 0 conflicts verified).
// grid=448, block=512 (8 waves 4Mx2N, wave 64co x 112n, acc 4x7).
// ---------------------------------------------------------------------------

#define BAR()    __builtin_amdgcn_s_barrier()
#define LGKM0()  asm volatile("s_waitcnt lgkmcnt(0)" ::: "memory")
#define VMW(N)   asm volatile("s_waitcnt vmcnt(" #N ")" ::: "memory")
#define SCHED0() __builtin_amdgcn_sched_barrier(0)
#define PRIO(x)  __builtin_amdgcn_s_setprio(x)

// stage body (tapS,cicS) into buf P: A 256x64 (4 loads/wave) + B 256x64
// (4 loads/wave). Advances tapS/cicS.
#define STAGE8(P) do {                                                        \
    const int kh2 = (tapS * 11) >> 5;                                         \
    const int kw2 = tapS - 3 * kh2;                                           \
    const int aOff = tapS * 65536 + cicS * 64;                                \
    const int bOff = ((kh2 - 1) * 30 + (kw2 - 1)) * 256 + cicS * 64;          \
    _Pragma("unroll") for (int c_ = 0; c_ < 4; ++c_)                          \
        __builtin_amdgcn_global_load_lds(                                     \
            (const AS1 void*)(aSrc + aOff + c_ * 16384),                      \
            (AS3 void*)(lds + (P)*65536 + c_*8192 + wave*1024 + lane*16),     \
            16, 0, 0);                                                        \
    _Pragma("unroll") for (int c_ = 0; c_ < 4; ++c_)                          \
        __builtin_amdgcn_global_load_lds(                                     \
            (const AS1 void*)(bL[c_] + bOff),                                 \
            (AS3 void*)(lds + (P)*65536 + 32768 + c_*8192 + wave*1024 + lane*16), \
            16, 0, 0);                                                        \
    if (++cicS == 4) { cicS = 0; ++tapS; }                                    \
} while (0)

// read fragment set S (L or H) for k-half KK from buf P (R3 formulas)
#define READF(S, P, KK) do {                                                  \
    _Pragma("unroll") for (int m_ = 0; m_ < 4; ++m_)                          \
        fa##S[m_] = *(const bf16x8*)(lds + (P)*65536 +                        \
            (wm*64 + m_*16 + l15)*128 + (frag_sw ^ ((KK)*64)));               \
    _Pragma("unroll") for (int f_ = 0; f_ < 7; ++f_)                          \
        fb##S[f_] = *(const bf16x8*)(lds + (P)*65536 + 32768 +                \
            (wn*112 + f_*16 + l15)*128 + (frag_sw ^ ((KK)*64)));              \
} while (0)

#define MFMA28(S) do {                                                        \
    _Pragma("unroll") for (int m_ = 0; m_ < 4; ++m_)                          \
    _Pragma("unroll") for (int f_ = 0; f_ < 7; ++f_)                          \
        acc[m_][f_] = __builtin_amdgcn_mfma_f32_16x16x32_bf16(                \
            fb##S[f_], fa##S[m_], acc[m_][f_], 0, 0, 0);                      \
} while (0)

// body with compile-time buf P; DO_STAGE: stage next body into P^1
#define BODY(P, DO_STAGE) do {                                                \
    VMW(0);                                                                   \
    SCHED0();                                                                 \
    BAR();                                                                    \
    READF(L, P, 0);                                                           \
    if (DO_STAGE) STAGE8((P)^1);                                              \
    SCHED0();                                                                 \
    LGKM0();                                                                  \
    PRIO(1); MFMA28(L); PRIO(0);                                              \
    READF(H, P, 1);                                                           \
    LGKM0();                                                                  \
    PRIO(1); MFMA28(H); PRIO(0);                                              \
    SCHED0();                                                                 \
} while (0)

__global__ __launch_bounds__(512, 2) void conv_gemm_kernel(
    const unsigned short* __restrict__ xm,
    const unsigned short* __restrict__ wB,
    float* __restrict__ out) {
    __shared__ __align__(1024) char lds[131072];   // 2 x (A 32KB + B 32KB)

    const int tid  = threadIdx.x;
    const int wave = tid >> 6;             // 0..7
    const int lane = tid & 63;
    const int l15  = lane & 15;
    const int n0   = blockIdx.x * 224;
    const int wm   = wave >> 1;            // 0..3 co quarter (64)
    const int wn   = wave & 1;             // 0..1 n half (112)

    // ---- staging sources (pre-swizzled k slot; R3-verified formulas) ----
    const int swzE = 8 * ((lane & 7) ^ (lane >> 3));   // elems within 64-k row
    const unsigned short* aSrc = wB + (wave * 8 + (lane >> 3)) * 256 + swzE;

    const unsigned short* bL[4];
    #pragma unroll
    for (int c_ = 0; c_ < 4; ++c_) {
        int nl = c_ * 64 + wave * 8 + (lane >> 3);     // 0..255
        nl = nl > 223 ? 223 : nl;                      // pad rows duplicate
        const int n  = n0 + nl;
        const int w_ = n % 28, h_ = (n / 28) % 28, bt = n / 784;
        bL[c_] = xm + (size_t)((bt * 30 + h_ + 1) * 30 + (w_ + 1)) * 256 + swzE;
    }

    // ---- fragment read swizzle (R3-verified, 128B rows) ----
    const int frag_sw = ((lane >> 4) * 16) ^ ((lane & 7) << 4);

    f32x4 acc[4][7];
    #pragma unroll
    for (int i = 0; i < 4; ++i)
        #pragma unroll
        for (int j = 0; j < 7; ++j) acc[i][j] = f32x4{0.f, 0.f, 0.f, 0.f};

    bf16x8 faL[4], fbL[7], faH[4], fbH[7];

    int tapS = 0, cicS = 0;
    // ---- prologue: stage S(0) -> buf0 ----
    STAGE8(0);

    // bodies j=0..35; body j: buf j&1, stages S(j+1) (except last)
    #pragma unroll 1
    for (int it = 0; it < 17; ++it) {
        BODY(0, 1);                // j even: stage -> buf1
        BODY(1, 1);                // j odd:  stage -> buf0
    }
    BODY(0, 1);                    // j=34: stage S(35) -> buf1
    BODY(1, 0);                    // j=35: no stage

    // ---- C-write: lane holds 4 consecutive n (rows) at one co (col) ----
    #pragma unroll
    for (int f = 0; f < 7; ++f) {
        const int n  = n0 + wn * 112 + f * 16 + ((lane >> 4) << 2);
        const int bt = n / 784;
        const int hw = n - bt * 784;
        const int b = bt >> 4, t = bt & 15;
        float* obase = out + ((size_t)(b * 256) * 16 + t) * 784 + hw;
        #pragma unroll
        for (int m = 0; m < 4; ++m) {
            const int co = wm * 64 + m * 16 + l15;
            *(f32x4*)(obase + (size_t)co * 12544) = acc[m][f];
        }
    }
}

// ---------------------------------------------------------------------------
extern "C" void kernel_launch(void* const* d_in, const int* in_sizes, int n_in,
                              void* d_out, int out_size, void* d_ws, size_t ws_size,
                              hipStream_t stream) {
    const float* x      = (const float*)d_in[0];
    const float* alpha  = (const float*)d_in[1];
    const float* weight = (const float*)d_in[2];
    float* out = (float*)d_out;

    unsigned short* xm = (unsigned short*)d_ws;
    unsigned short* wB = (unsigned short*)((char*)d_ws + XM_BYTES);

    modulate_kernel<<<dim3(NB * NT * HP), dim3(256), 0, stream>>>(x, alpha, xm);
    repack_w_kernel<<<dim3(9 * 256), dim3(256), 0, stream>>>(weight, wB);
    conv_gemm_kernel<<<dim3(448), dim3(512), 0, stream>>>(xm, wB, out);
}